// Round 6
// baseline (251.018 us; speedup 1.0000x reference)
//
#include <hip/hip_runtime.h>
#include <cfloat>

// VectorQuantizer: N=32768 rows, K=8192 codes, D=256, fp32.
// R2/R3 (absmax 0): reference = numpy fp32; d_k = fl32(fl32(x2+wn_k)-fl32(2*m_k)),
// m_k = single fp32 FMA chain d-ascending; first-occurrence argmin. Exact top-8
// rescore of approximate-scorer candidates reproduces it bit-for-bit.
// R6 (125.3us score): 2x32KB dbuf + per-kt syncthreads. 0 bank conflicts.
// R7 (140us): deferred-SEL w/ 4 acc sets -> spill (WRITE 1024->6656KB). Reverted.
// R10 (119.4us, absmax 0): barrier-FREE per-wave counted-vmcnt pipeline (each
//   wave stages+reads only its own LDS quarter). Gain small; MfmaUtil 24%.
//   => barrier drain was NOT the stall. Stall is INTRA-WAVE: per kt the wave is
//   a serial chain [ds_read waits -> 4-deep MFMA dep chains -> SEL(reads this
//   kt's acc) -> INIT(WAR on SEL)], ~4479 cyc wall vs ~550 MFMA issue + ~340
//   VALU; 2 phase-identical waves/SIMD collide on the same pipe (sum not max).
// R12 (this round): DEFERRED selection without R7's spill:
//   - end of iter kt: KEYX extracts 32 u32 keys from acc (and/or) -> pk[2][16];
//     acc regs die, INIT of next iter is WAR-free.
//   - iter kt+1: SELCH chunks (8 keys x 3 ops) of pk interleaved BETWEEN the
//     MFMA steps -- independent of in-flight MFMAs (touch only s0/s1) -> wave
//     issues VALU into its own MFMA stalls; SIMD overlaps the 2 waves' pipes.
//   - B-fragments: explicit 1-ahead register double-buffer (bofs[ks+1] read
//     issued before ks's MFMAs) so ds_read latency stops gating each step.
//   - key multiset identical, (min,2nd-min) maintenance order-independent,
//     same arithmetic ops => bit-exact vs R6/R10. First iter SELCHes dummy
//     0xFFFFFFFF keys (provably no-op: min/max identities).
//   - est live regs ~240 (af 64 + s0s1 64 + acc 32 + pk 32 + B 16 + addr);
//     2-wave/SIMD budget 256; LDS still fixes 2 blocks/CU. Watch: WRITE_SIZE
//     must stay 1024KB (spill tripwire).
// prep_w / rescore untouched (bit-exact verified).

#define DDIM 256

typedef int   i32x8  __attribute__((ext_vector_type(8)));
typedef float f32x16 __attribute__((ext_vector_type(16)));

// ---------- W prep: numpy-exact ||w||^2 + negated scaled fp8 ----------
__global__ __launch_bounds__(256) void vq_prep_w(
    const float* __restrict__ w, float* __restrict__ wn,
    unsigned char* __restrict__ wb8) {
    __shared__ float rows[32 * 260];
    const int tid = threadIdx.x;
    const int r0 = blockIdx.x * 32;

    for (int idx = tid; idx < 32 * 64; idx += 256) {
        int r = idx >> 6, c4 = idx & 63;
        *(float4*)&rows[r * 260 + c4 * 4] =
            *(const float4*)(w + (size_t)(r0 + r) * DDIM + c4 * 4);
    }
    __syncthreads();
    {
        // numpy pairwise_sum(fl(a*a),256): two 128-halves, each 8 stride-8
        // chains, ((r0+r1)+(r2+r3))+((r4+r5)+(r6+r7)); shfl-xor == nesting.
        const int row = (tid >> 6) * 8 + ((tid & 63) >> 3), j = tid & 7;
        const float* a = &rows[row * 260];
        float half[2];
#pragma unroll
        for (int h = 0; h < 2; ++h) {
            const float* b = a + h * 128 + j;
            float r = __fmul_rn(b[0], b[0]);
#pragma unroll
            for (int t = 1; t < 16; ++t)
                r = __fadd_rn(r, __fmul_rn(b[8 * t], b[8 * t]));
            float p = __fadd_rn(r, __shfl_xor(r, 1, 64));
            p = __fadd_rn(p, __shfl_xor(p, 2, 64));
            p = __fadd_rn(p, __shfl_xor(p, 4, 64));
            half[h] = p;
        }
        if (j == 0) wn[r0 + row] = __fadd_rn(half[0], half[1]);
    }
    // fp8 e4m3 emission, scaled by -2^13 (pow2 cancels in argmin; negation
    // folds the "-2m" sign so acc = C - m_s with C=128 init)
    for (int idx = tid; idx < 32 * 16; idx += 256) {
        int r = idx >> 4, s = idx & 15;
        const float* p = &rows[r * 260 + s * 16];
        unsigned q[4];
#pragma unroll
        for (int m = 0; m < 4; ++m) {
            unsigned v = (unsigned)__builtin_amdgcn_cvt_pk_fp8_f32(
                p[m * 4 + 0] * -8192.f, p[m * 4 + 1] * -8192.f, 0, false);
            v = (unsigned)__builtin_amdgcn_cvt_pk_fp8_f32(
                p[m * 4 + 2] * -8192.f, p[m * 4 + 3] * -8192.f, (int)v, true);
            q[m] = v;
        }
        *(uint4*)(wb8 + (size_t)(r0 + r) * DDIM + s * 16) =
            make_uint4(q[0], q[1], q[2], q[3]);
    }
}

// ---------- MX-fp8 scorer: 64 rows x 8192 cols per block, 2 blocks/CU ----------
// 256 thr = 4 waves (wave = 32-col group); wave tile 64r x 32c = 2 MFMA
// 32x32x64 tiles. A resident in VGPRs. W 128c x 256k = 32 KB tiles, 2 buffers,
// global_load_lds (16B), XOR-swizzled granules (R6 map, ZERO bank conflicts).
// C/D (32x32): col=lane&31, row=(reg&3)+8*(reg>>2)+4*(lane>>5)  [m74/m101].

#define VWAIT(n) do { \
    asm volatile("s_waitcnt vmcnt(" #n ")" ::: "memory"); \
    __builtin_amdgcn_sched_barrier(0); \
  } while (0)

#define INIT128(C) { _Pragma("unroll") for (int r_ = 0; r_ < 16; ++r_) (C)[r_] = 128.0f; }

// deferred compare-update of 8 previous-kt keys (rows ks*4..ks*4+3, both rt).
// Touches only pk/s0/s1 -- independent of in-flight MFMAs. Order-independent
// (min,2nd-min) maintenance == R6 sequence on the same key multiset.
#define SELCH(ks) { \
    _Pragma("unroll") for (int j_ = 0; j_ < 4; ++j_) { \
        const int r_ = (ks) * 4 + j_; \
        _Pragma("unroll") for (int rt_ = 0; rt_ < 2; ++rt_) { \
            unsigned key_ = pk[rt_][r_]; \
            unsigned a0_ = s0[rt_][r_]; \
            unsigned mx_ = key_ > a0_ ? key_ : a0_; \
            s1[rt_][r_] = mx_ < s1[rt_][r_] ? mx_ : s1[rt_][r_]; \
            s0[rt_][r_] = key_ < a0_ ? key_ : a0_; \
        } } }

// key extraction for THIS kt (depends on completed acc; 64 VALU tail)
#define KEYX(pkt) { \
    const unsigned colv_ = (unsigned)((pkt) * 128 + bcol); \
    _Pragma("unroll") for (int r_ = 0; r_ < 16; ++r_) { \
        pk[0][r_] = (__float_as_uint(acc0[r_]) & 0xFFFFE000u) | colv_; \
        pk[1][r_] = (__float_as_uint(acc1[r_]) & 0xFFFFE000u) | colv_; \
    } }

// one ks step: prefetch next B pair, 2 MFMAs on current, deferred SEL chunk
#define STEP(ks, BC, BN, NK, TGL) do { \
    if (NK) { \
        BN.q[0] = *(const uint4*)(wsb + (TGL) + bofs[(ks) + 1][0]); \
        BN.q[1] = *(const uint4*)(wsb + (TGL) + bofs[(ks) + 1][1]); \
    } \
    acc0 = __builtin_amdgcn_mfma_scale_f32_32x32x64_f8f6f4( \
        af[0][ks], BC.v, acc0, 0, 0, 0, 0x7F7F7F7F, 0, 0x7F7F7F7F); \
    acc1 = __builtin_amdgcn_mfma_scale_f32_32x32x64_f8f6f4( \
        af[1][ks], BC.v, acc1, 0, 0, 0, 0x7F7F7F7F, 0, 0x7F7F7F7F); \
    SELCH(ks); \
  } while (0)

__global__ __launch_bounds__(256, 2) void vq_score(
    const float* __restrict__ x, const unsigned char* __restrict__ wb8,
    unsigned* __restrict__ cand) {
    __shared__ __align__(16) unsigned char Ws[2][32768];
    const int tid = threadIdx.x;
    const int wave = tid >> 6, lane = tid & 63;
    const int h = lane >> 5, c32 = lane & 31;
    const int rowBase = blockIdx.x * 64;
    const unsigned char* wsb = (const unsigned char*)&Ws[0][0];

    // A fragments: 64 rows x 256 k fp8, converted from fp32 global (one-time)
    i32x8 af[2][4];
#pragma unroll
    for (int rt = 0; rt < 2; ++rt) {
        const float* xr = x + (size_t)(rowBase + rt * 32 + c32) * DDIM;
#pragma unroll
        for (int ks = 0; ks < 4; ++ks) {
            const float4* p = (const float4*)(xr + ks * 64 + h * 32);
            union { int d[8]; i32x8 v; } u;
#pragma unroll
            for (int m = 0; m < 8; ++m) {
                float4 f = p[m];
                unsigned v = (unsigned)__builtin_amdgcn_cvt_pk_fp8_f32(
                    f.x, f.y, 0, false);
                v = (unsigned)__builtin_amdgcn_cvt_pk_fp8_f32(
                    f.z, f.w, (int)v, true);
                u.d[m] = (int)v;
            }
            af[rt][ks] = u.v;
        }
    }
    // clean vmcnt baseline for the counted pipeline (drains the A loads)
    asm volatile("s_waitcnt vmcnt(0)" ::: "memory");

    // staging map (R6 VERBATIM): 4 waves x 8 instr x 64 lanes = 2048 granules
    // (16B) = 32 KB per tile. slot covers 4 cols; granule XOR-placed by col&15.
    // Wave w stages slots w*8..w*8+7 = its own read region -> no cross-wave flow.
    unsigned sOfs[8], ldsOfs[8];
#pragma unroll
    for (int i = 0; i < 8; ++i) {
        int slot = wave * 8 + i;                  // 0..31
        int col  = slot * 4 + (lane >> 4);        // 0..127
        int gsrc = (lane & 15) ^ (col & 15);      // XOR bank spread
        sOfs[i]   = (unsigned)(col * 256 + gsrc * 16);
        ldsOfs[i] = (unsigned)(slot * 1024);      // + lane*16 implicit
    }
    auto stage = [&](int kt, unsigned tgl) {
        const unsigned char* g = wb8 + (size_t)kt * 32768;
#pragma unroll
        for (int i = 0; i < 8; ++i)
            __builtin_amdgcn_global_load_lds(
                (const __attribute__((address_space(1))) unsigned int*)(g + sOfs[i]),
                (__attribute__((address_space(3))) unsigned int*)(
                    &Ws[0][0] + tgl + ldsOfs[i]),
                16, 0, 0);
    };

    // B-fragment read offsets (R6 VERBATIM): granule gb of col bcol sits at
    // bcol*256 + (gb^(bcol&15))*16 within a 32KB buffer.
    const int bcol = wave * 32 + c32, cs = bcol & 15;
    int bofs[4][2];
#pragma unroll
    for (int ks = 0; ks < 4; ++ks) {
        int gb = ks * 4 + h * 2;
        bofs[ks][0] = bcol * 256 + ((gb)     ^ cs) * 16;
        bofs[ks][1] = bcol * 256 + ((gb + 1) ^ cs) * 16;
    }

    unsigned s0[2][16], s1[2][16], pk[2][16];
#pragma unroll
    for (int a = 0; a < 2; ++a)
#pragma unroll
        for (int r = 0; r < 16; ++r) {
            s0[a][r] = 0xFFFFFFFFu; s1[a][r] = 0xFFFFFFFFu; pk[a][r] = 0xFFFFFFFFu;
        }

    f32x16 acc0, acc1;
    union Bu { uint4 q[2]; i32x8 v; };
    Bu bA, bB;

    // Per-wave pipeline ledger (8 loads/wave/tile):
    //   stage(0)->buf0 [8]; iter kt<63: stage(kt+1)->other buf [16];
    //   vmcnt(8) -> tile kt landed, kt+1 in flight; peeled 63: vmcnt(0).
    //   SELCH in iter kt processes keys of kt-1 (dummy no-op keys at kt=0);
    //   KEYX at iter end rebuilds pk from this kt's acc (after SELCH reads).
    stage(0, 0);

    for (int kt = 0; kt < 63; ++kt) {
        const unsigned tgl = (unsigned)(kt & 1) << 15;
        stage(kt + 1, tgl ^ 32768u);
        INIT128(acc0); INIT128(acc1);
        VWAIT(8);
        bA.q[0] = *(const uint4*)(wsb + tgl + bofs[0][0]);
        bA.q[1] = *(const uint4*)(wsb + tgl + bofs[0][1]);
        __builtin_amdgcn_s_setprio(1);
        STEP(0, bA, bB, 1, tgl);
        STEP(1, bB, bA, 1, tgl);
        STEP(2, bA, bB, 1, tgl);
        STEP(3, bB, bA, 0, tgl);
        __builtin_amdgcn_s_setprio(0);
        KEYX(kt);
    }
    // kt = 63 (peeled tail): drain and compute buf1
    {
        INIT128(acc0); INIT128(acc1);
        VWAIT(0);
        bA.q[0] = *(const uint4*)(wsb + 32768 + bofs[0][0]);
        bA.q[1] = *(const uint4*)(wsb + 32768 + bofs[0][1]);
        __builtin_amdgcn_s_setprio(1);
        STEP(0, bA, bB, 1, 32768u);
        STEP(1, bB, bA, 1, 32768u);
        STEP(2, bA, bB, 1, 32768u);
        STEP(3, bB, bA, 0, 32768u);
        __builtin_amdgcn_s_setprio(0);
        KEYX(63);
        // epilogue: fold kt=63's keys
        SELCH(0); SELCH(1); SELCH(2); SELCH(3);
    }

    // merge: 64 rows x 256 keys = 64 KB (reuse Ws) -- first cross-wave flow
    __syncthreads();
    unsigned* ms = (unsigned*)Ws;
#pragma unroll
    for (int rt = 0; rt < 2; ++rt)
#pragma unroll
        for (int r = 0; r < 16; ++r) {
            int rloc = rt * 32 + (r & 3) + 8 * (r >> 2) + 4 * h;
            *(uint2*)&ms[rloc * 256 + bcol * 2] = make_uint2(s0[rt][r], s1[rt][r]);
        }
    __syncthreads();
    if (tid < 64) {
        const uint4* rowk = (const uint4*)(ms + tid * 256);
        unsigned best[8];
#pragma unroll
        for (int i = 0; i < 8; ++i) best[i] = 0xFFFFFFFFu;
        for (int i = 0; i < 64; ++i) {
            uint4 qv = rowk[(i + tid) & 63];   // rotated: bank spread
            unsigned kk[4] = {qv.x, qv.y, qv.z, qv.w};
#pragma unroll
            for (int e = 0; e < 4; ++e) {
                unsigned key = kk[e];
                if (key < best[7]) {
                    best[7] = key;
#pragma unroll
                    for (int j = 7; j > 0; --j)
                        if (best[j] < best[j - 1]) {
                            unsigned t = best[j]; best[j] = best[j - 1]; best[j - 1] = t;
                        }
                }
            }
        }
        unsigned* out = cand + (size_t)(rowBase + tid) * 8;
#pragma unroll
        for (int i = 0; i < 8; ++i) out[i] = best[i];
    }
}

// ---------- exact rescore (fp32 chain, R3-verified) + inline numpy x2 ----------
__global__ __launch_bounds__(256) void vq_rescore_write(
    const float* __restrict__ x, const float* __restrict__ w,
    const float* __restrict__ wn, const unsigned* __restrict__ cand,
    float* __restrict__ outq, float* __restrict__ outi) {
    __shared__ int winners[32];
    const int tid = threadIdx.x;
    const int lr = tid >> 3, cc = tid & 7;
    const int row = blockIdx.x * 32 + lr;

    int k = (int)(cand[(size_t)row * 8 + cc] & 0x1FFFu);
    const float* xr = x + (size_t)row * DDIM;
    const float* wr = w + (size_t)k * DDIM;
    // dot: single fp32 fmaf chain d-ascending (BLAS-exact, R2/R3-verified)
    // x2: numpy pairwise (two halves, 8 stride-8 chains, exact nesting)
    float dot = 0.f;
    float half[2];
#pragma unroll
    for (int hh = 0; hh < 2; ++hh) {
        float r[8];
#pragma unroll
        for (int t = 0; t < 16; ++t) {
            const int d = hh * 128 + t * 8;
            float4 xa = *(const float4*)(xr + d);
            float4 xb = *(const float4*)(xr + d + 4);
            float4 wa = *(const float4*)(wr + d);
            float4 wb = *(const float4*)(wr + d + 4);
            dot = __fmaf_rn(xa.x, wa.x, dot); dot = __fmaf_rn(xa.y, wa.y, dot);
            dot = __fmaf_rn(xa.z, wa.z, dot); dot = __fmaf_rn(xa.w, wa.w, dot);
            dot = __fmaf_rn(xb.x, wb.x, dot); dot = __fmaf_rn(xb.y, wb.y, dot);
            dot = __fmaf_rn(xb.z, wb.z, dot); dot = __fmaf_rn(xb.w, wb.w, dot);
            if (t == 0) {
                r[0] = __fmul_rn(xa.x, xa.x); r[1] = __fmul_rn(xa.y, xa.y);
                r[2] = __fmul_rn(xa.z, xa.z); r[3] = __fmul_rn(xa.w, xa.w);
                r[4] = __fmul_rn(xb.x, xb.x); r[5] = __fmul_rn(xb.y, xb.y);
                r[6] = __fmul_rn(xb.z, xb.z); r[7] = __fmul_rn(xb.w, xb.w);
            } else {
                r[0] = __fadd_rn(r[0], __fmul_rn(xa.x, xa.x));
                r[1] = __fadd_rn(r[1], __fmul_rn(xa.y, xa.y));
                r[2] = __fadd_rn(r[2], __fmul_rn(xa.z, xa.z));
                r[3] = __fadd_rn(r[3], __fmul_rn(xa.w, xa.w));
                r[4] = __fadd_rn(r[4], __fmul_rn(xb.x, xb.x));
                r[5] = __fadd_rn(r[5], __fmul_rn(xb.y, xb.y));
                r[6] = __fadd_rn(r[6], __fmul_rn(xb.w == xb.w ? xb.z : xb.z, xb.z));
                r[7] = __fadd_rn(r[7], __fmul_rn(xb.w, xb.w));
            }
        }
        half[hh] = __fadd_rn(__fadd_rn(__fadd_rn(r[0], r[1]), __fadd_rn(r[2], r[3])),
                             __fadd_rn(__fadd_rn(r[4], r[5]), __fadd_rn(r[6], r[7])));
    }
    float x2v = __fadd_rn(half[0], half[1]);
    float dv = __fsub_rn(__fadd_rn(x2v, wn[k]), __fmul_rn(2.0f, dot));
    // lexicographic (dv,k) min across 8 candidate lanes (first-occurrence)
#pragma unroll
    for (int m = 1; m < 8; m <<= 1) {
        float od = __shfl_xor(dv, m, 64);
        int   ok = __shfl_xor(k,  m, 64);
        if (od < dv || (od == dv && ok < k)) { dv = od; k = ok; }
    }
    if (cc == 0) winners[lr] = k;
    __syncthreads();
    if (tid < 32) outi[blockIdx.x * 32 + tid] = (float)winners[tid];
    for (int u = tid; u < 32 * 64; u += 256) {
        int r = u >> 6, c4 = u & 63;
        *reinterpret_cast<float4*>(outq + (size_t)(blockIdx.x * 32 + r) * DDIM + c4 * 4) =
            *reinterpret_cast<const float4*>(w + (size_t)winners[r] * DDIM + c4 * 4);
    }
}

extern "C" void kernel_launch(void* const* d_in, const int* in_sizes, int n_in,
                              void* d_out, int out_size, void* d_ws, size_t ws_size,
                              hipStream_t stream) {
    const float* x = (const float*)d_in[0];
    const float* w = (const float*)d_in[1];
    const int N = in_sizes[0] / DDIM;   // 32768
    const int K = in_sizes[1] / DDIM;   // 8192
    float* outq = (float*)d_out;
    float* outi = outq + (size_t)N * DDIM;

    unsigned char* wb8 = (unsigned char*)d_ws;                // K*256 = 2 MB
    float* wn = (float*)(wb8 + (size_t)K * DDIM);             // K floats
    unsigned* cand = (unsigned*)(wn + K);                     // N*8 u32 = 1 MB

    hipLaunchKernelGGL(vq_prep_w, dim3(K / 32), dim3(256), 0, stream, w, wn, wb8);
    hipLaunchKernelGGL(vq_score, dim3(N / 64), dim3(256), 0, stream, x, wb8, cand);
    hipLaunchKernelGGL(vq_rescore_write, dim3(N / 32), dim3(256), 0, stream,
                       x, w, wn, cand, outq, outi);
}